// Round 9
// baseline (54.354 us; speedup 1.0000x reference)
//
#include <hip/hip_runtime.h>
#include <hip/hip_bf16.h>

// CombinedRotaryEmbedding via MFMA.
// prep (1 wave): fold Givens chain into rotation_matrix -> M (64x64), apply
//   RoPE even/odd column permutation, quantize to bf16, store as
//   mfma_f32_16x16x32_bf16 B-fragments (8 KB) in d_ws.
// main: TWO tokens per wave, fully unrolled straight-line (no loop -> no
//   B-fragment rematerialization, the R5 failure mode). Per token:
//   contiguous 1KB dwordx4 loads -> XOR-swizzled per-wave LDS -> A frags ->
//   2-term bf16-split MFMA -> RoPE epilogue -> LDS -> contiguous 1KB
//   nontemporal stores. R8 post-mortem: 54.2us = 79% of copy ceiling;
//   residual = per-wave fixed costs (8KB B-table reload per wave, wave
//   start/drain) -> halve wave count, amortize B over 2 tokens.

#define N_TILES 32768                   // B*S tokens
#define N_BLOCKS (N_TILES / 8)          // 4096 blocks, 2 tokens per wave

typedef __attribute__((ext_vector_type(8))) short short8;
typedef __attribute__((ext_vector_type(4))) float f32x4;

__device__ __forceinline__ unsigned short f2bf_bits(float f) {
  return __bfloat16_as_ushort(__float2bfloat16(f));
}

__global__ __launch_bounds__(64) void prep_kernel(
    const float* __restrict__ thetas,
    const float* __restrict__ R,
    short* __restrict__ Bws) {
  const int t = threadIdx.x;  // 0..63
  float col[64];
#pragma unroll
  for (int d = 0; d < 64; ++d) col[d] = R[d * 64 + t];
  // M = G0 G1 ... G31 R ; Gk mixes rows k,k+1 (lane-local here).
#pragma unroll
  for (int k = 31; k >= 0; --k) {
    float th = thetas[k];
    float ck = cosf(th), sk = sinf(th);
    float a = col[k], b = col[k + 1];
    col[k]     = ck * a - sk * b;
    col[k + 1] = sk * a + ck * b;
  }
  __shared__ float Ml[64][64];
#pragma unroll
  for (int d = 0; d < 64; ++d) Ml[d][t] = col[d];
  __syncthreads();

  // B fragment for mfma_f32_16x16x32_bf16: col=lane&15, k=(lane>>4)*8+e.
  short8* Bp = (short8*)Bws;
  const int cb = t & 15, kg = t >> 4;
#pragma unroll
  for (int s = 0; s < 2; ++s) {
#pragma unroll
    for (int nt = 0; nt < 4; ++nt) {
      const int c2 = cb + 16 * nt;
      const int pc = (c2 < 32) ? (2 * c2) : (2 * (c2 - 32) + 1);  // RoPE perm
      short8 hf;
#pragma unroll
      for (int e = 0; e < 8; ++e) {
        const int k = s * 32 + kg * 8 + e;
        hf[e] = (short)f2bf_bits(Ml[k][pc]);
      }
      Bp[(s * 4 + nt) * 64 + t] = hf;
    }
  }
}

__global__ __launch_bounds__(256, 4) void rope_mfma(
    const float* __restrict__ x,
    const float* __restrict__ inv_freq,
    const short* __restrict__ Bws,
    float* __restrict__ out) {
  const int lane = threadIdx.x & 63;
  const int wid = threadIdx.x >> 6;
  const int cb = lane & 15;   // A row within tile / D col within 16-block
  const int kg = lane >> 4;   // k-group

  const int tile0 = (int)blockIdx.x * 8 + wid * 2;   // first of 2 tokens

  __shared__ alignas(16) float stage[4][2][16 * 64];

  // --- Issue ALL global loads up front: 8 KB of x + 8 KB B-table. ---
  const f32x4* xb = (const f32x4*)(x + (size_t)tile0 * 1024);
  f32x4 va[2][4];
#pragma unroll
  for (int tt = 0; tt < 2; ++tt)
#pragma unroll
    for (int j = 0; j < 4; ++j) va[tt][j] = xb[tt * 256 + j * 64 + lane];

  const short8* Bp = (const short8*)Bws;
  short8 bh[8];
#pragma unroll
  for (int i = 0; i < 8; ++i) bh[i] = Bp[i * 64 + lane];

  // sincos for both tokens, in the load shadow.
  const float iv0 = inv_freq[cb];
  const float iv1 = inv_freq[cb + 16];
  float sv0[2], cv0[2], sv1[2], cv1[2];
#pragma unroll
  for (int tt = 0; tt < 2; ++tt) {
    const int pos = (tile0 + tt) & 8191;
    __sincosf((float)pos * iv0, &sv0[tt], &cv0[tt]);
    __sincosf((float)pos * iv1, &sv1[tt], &cv1[tt]);
  }

  // --- Stage both tokens into LDS early (overlaps with B-load wait). ---
#pragma unroll
  for (int tt = 0; tt < 2; ++tt) {
    float* st = stage[wid][tt];
    const int r0 = lane >> 4;       // row sub-index 0..3
    const int c16 = lane & 15;      // source chunk
#pragma unroll
    for (int j = 0; j < 4; ++j) {
      const int row = j * 4 + r0;
      *(f32x4*)&st[row * 64 + (((c16 ^ row) & 15) << 2)] = va[tt][j];
    }
  }

#pragma unroll
  for (int tt = 0; tt < 2; ++tt) {
    float* st = stage[wid][tt];
    const size_t rb = (size_t)(tile0 + tt) * 16;

    // A-fragments: lane's row = cb, cols [s*32+kg*8, +8).
    float af[2][8];
#pragma unroll
    for (int s = 0; s < 2; ++s) {
#pragma unroll
      for (int t2 = 0; t2 < 2; ++t2) {
        const int ch = s * 8 + kg * 2 + t2;   // original 16B chunk index
        f32x4 q = *(const f32x4*)&st[cb * 64 + (((ch ^ cb) & 15) << 2)];
        af[s][t2 * 4 + 0] = q.x;
        af[s][t2 * 4 + 1] = q.y;
        af[s][t2 * 4 + 2] = q.z;
        af[s][t2 * 4 + 3] = q.w;
      }
    }

    // 2-term hi/lo bf16 split (absmax ~0.031 vs 0.118 threshold).
    short8 ah[2], al[2];
#pragma unroll
    for (int s = 0; s < 2; ++s) {
#pragma unroll
      for (int e = 0; e < 8; ++e) {
        float f = af[s][e];
        __hip_bfloat16 h = __float2bfloat16(f);
        ah[s][e] = (short)__bfloat16_as_ushort(h);
        al[s][e] = (short)f2bf_bits(f - __bfloat162float(h));
      }
    }

    f32x4 acc[4];
#pragma unroll
    for (int nt = 0; nt < 4; ++nt) acc[nt] = (f32x4){0.f, 0.f, 0.f, 0.f};
#pragma unroll
    for (int s = 0; s < 2; ++s) {
#pragma unroll
      for (int nt = 0; nt < 4; ++nt) {
        acc[nt] = __builtin_amdgcn_mfma_f32_16x16x32_bf16(ah[s], bh[s * 4 + nt], acc[nt], 0, 0, 0);
        acc[nt] = __builtin_amdgcn_mfma_f32_16x16x32_bf16(al[s], bh[s * 4 + nt], acc[nt], 0, 0, 0);
      }
    }

    // RoPE combine -> same LDS region (per-wave DS is in-order: WAR safe).
#pragma unroll
    for (int nt = 0; nt < 4; ++nt) {
      const float cvx = (nt & 1) ? cv1[tt] : cv0[tt];
      const float ssv = ((nt & 1) ? sv1[tt] : sv0[tt]) * ((nt < 2) ? -1.f : 1.f);
      const int chunk = (cb >> 2) + 4 * nt;
      const int c1i = cb & 3;
#pragma unroll
      for (int r = 0; r < 4; ++r) {
        const int lrow = kg * 4 + r;
        float y = acc[nt][r];
        float p = acc[nt ^ 2][r];
        st[lrow * 64 + ((chunk ^ lrow) << 2) + c1i] = fmaf(p, ssv, y * cvx);
      }
    }
    asm volatile("s_waitcnt lgkmcnt(0)");

    // 4 contiguous 1 KB nontemporal stores.
#pragma unroll
    for (int i = 0; i < 4; ++i) {
      const int g = i * 4 + kg;                      // output row within tile
      const f32x4 v = *(const f32x4*)&st[g * 64 + ((cb ^ g) << 2)];
      __builtin_nontemporal_store(v, (f32x4*)(out + (rb + g) * 64) + cb);
    }
  }
}

extern "C" void kernel_launch(void* const* d_in, const int* in_sizes, int n_in,
                              void* d_out, int out_size, void* d_ws, size_t ws_size,
                              hipStream_t stream) {
  const float* x        = (const float*)d_in[0];
  const float* thetas   = (const float*)d_in[1];
  const float* R        = (const float*)d_in[2];
  const float* inv_freq = (const float*)d_in[3];

  prep_kernel<<<1, 64, 0, stream>>>(thetas, R, (short*)d_ws);
  rope_mfma<<<N_BLOCKS, 256, 0, stream>>>(x, inv_freq, (const short*)d_ws, (float*)d_out);
}